// Round 9
// baseline (607.896 us; speedup 1.0000x reference)
//
#include <hip/hip_runtime.h>
#include <hip/hip_bf16.h>

// CapsuleLayerWithRouting: batch=128, in_caps=1152, in_hid=16, out_caps=32,
// out_hid=16, 3 routing iterations (fixed). fp32 in/out.
//
// Round-9: revert to the round-5 structure (best passing, 165us: P-slab
// plain stores + tiny reduce/squash kernels; atomics-into-S of rounds 7/8
// proved 1.5-2.6x slower), then attack its limiter (latency-bound Wb fetch
// at 2 blocks/CU):
//  - IPC 18->9: grid = 128 iblk x 8 bg = 1024 blocks = 4 blocks/CU,
//    __launch_bounds__(512,8) (VGPR cap 64 >= measured 48, LDS ~11 KB)
//    -> 2x in-flight loads, 4-deep per-CU block pipelining
//  - bx = bg*128 + iblk keeps all 8 sharers of a Wb slice on XCD iblk%8;
//    per-XCD Wb footprint 16*144KB = 2.3MB < 4MB L2 -> pass2/3 L2 reuse
//  - no atomics, no memsets, no counters; P fully overwritten each pass
// Fragment layouts (HW-verified m89/m91):
//   A[m=lane&15][k=(lane>>4)*8+j]  B[k=(lane>>4)*8+j][n=lane&15]
//   D[row=(lane>>4)*4+reg][col=lane&15];  K padded 16->32 via zeros in xs.

#define IN_CAPS 1152
#define IPC 9
#define NBLK_I 128                           // 1152/9
#define SV_ELEMS 65536                       // 128*32*16

typedef __attribute__((ext_vector_type(8))) short short8;
typedef __attribute__((ext_vector_type(4))) float f32x4;

__device__ inline unsigned f2bf(float x) {   // RNE fp32 -> bf16
  unsigned u = __builtin_bit_cast(unsigned, x);
  return (u + 0x7FFFu + ((u >> 16) & 1u)) >> 16;
}

// ---- W [1152][16][512] fp32 -> Wb [i][o][lane(32)][8] bf16 (A-frag);
// LDS-staged so reads and writes are both coalesced. ----
__global__ __launch_bounds__(256)
void conv_w(const float* __restrict__ W, unsigned short* __restrict__ Wb) {
  __shared__ float st[16 * 516];
  const int t = threadIdx.x;
  const size_t ibase = (size_t)blockIdx.x * 8192;
  const float4* src = (const float4*)(W + ibase);
#pragma unroll
  for (int r = 0; r < 8; ++r) {
    const int f = r * 256 + t;                // 0..2047 float4s
    const int k = f >> 7, c4 = f & 127;
    *(float4*)&st[k * 516 + c4 * 4] = src[f];
  }
  __syncthreads();
  unsigned short* dst = Wb + ibase;
#pragma unroll
  for (int r = 0; r < 4; ++r) {
    const int u = r * 256 + t;                // 0..1023 = o*32 + l
    const int o = u >> 5, l = u & 31;
    const int col = o * 16 + (l & 15), k0 = (l >> 4) * 8;
    unsigned b[8];
#pragma unroll
    for (int j = 0; j < 8; ++j) b[j] = f2bf(st[(k0 + j) * 516 + col]);
    uint4 outv;
    outv.x = b[0] | (b[1] << 16);
    outv.y = b[2] | (b[3] << 16);
    outv.z = b[4] | (b[5] << 16);
    outv.w = b[6] | (b[7] << 16);
    *(uint4*)(dst + (size_t)u * 8) = outv;    // consecutive u -> coalesced
  }
}

// ---- x B-fragment slice in LDS; zeros in lanes 32-63 (K pad 16->32) ----
__device__ __forceinline__ void build_xs(const float* __restrict__ X, int bg,
                                         int i0, int t, unsigned (*xs)[64][4]) {
#pragma unroll
  for (int rep = 0; rep < (IPC * 256 + 511) / 512; ++rep) {   // 5 (last half)
    const int base = rep * 512 + t;
    if (base < IPC * 256) {
      const int ii = base >> 8;
      const int e = base & 255;
      const int l2 = e >> 2, ju = e & 3;
      unsigned val = 0;
      if (l2 < 32) {
        const float2 f = *(const float2*)(X +
            ((size_t)(bg * 16 + (l2 & 15)) * IN_CAPS + (i0 + ii)) * 16 +
            (l2 >> 4) * 8 + 2 * ju);
        val = f2bf(f.x) | (f2bf(f.y) << 16);
      }
      xs[ii][l2][ju] = val;
    }
  }
}

__device__ __forceinline__ short8 ld_x(const unsigned (*xs)[64][4], int ii, int l) {
  return __builtin_bit_cast(short8, *(const uint4*)(&xs[ii][l][0]));
}

// ---- pass kernel. PASS==1: C=1/32 uniform; PASS==2: dot/softmax/accum ----
template <int PASS>
__global__ __launch_bounds__(512, 8)
void caps_pass(const unsigned short* __restrict__ Wb,
               const float* __restrict__ X,
               const float* __restrict__ Vt,    // frag order (PASS==2)
               float* __restrict__ P) {         // [NBLK_I][128][512]
  __shared__ __align__(16) unsigned xs[IPC][64][4];   // 9.2 KB
  __shared__ float part[2][8][16];

  const int t = threadIdx.x, w = t >> 6, l = t & 63;
  const int q = l >> 4, bl = l & 15;
  const int bx = blockIdx.x, iblk = bx & 127, bg = bx >> 7;  // XCD = iblk%8
  const int i0 = iblk * IPC;

  f32x4 v[4], sacc[4];
#pragma unroll
  for (int m = 0; m < 4; ++m) {
    sacc[m] = (f32x4){0.f, 0.f, 0.f, 0.f};
    if constexpr (PASS == 2)
      v[m] = ((const f32x4*)Vt)[((size_t)(bg * 8 + w) * 64 + l) * 4 + m];
  }

  build_xs(X, bg, i0, t, xs);
  __syncthreads();

  const short8* wp = (const short8*)Wb + ((size_t)i0 * 32 + w * 4) * 32 + (l & 31);

  if constexpr (PASS == 1) {
    for (int ii = 0; ii < IPC; ++ii) {
      short8 x = ld_x(xs, ii, l);
      short8 a0 = wp[0], a1 = wp[32], a2 = wp[64], a3 = wp[96];
      wp += 1024;
      sacc[0] = __builtin_amdgcn_mfma_f32_16x16x32_bf16(a0, x, sacc[0], 0, 0, 0);
      sacc[1] = __builtin_amdgcn_mfma_f32_16x16x32_bf16(a1, x, sacc[1], 0, 0, 0);
      sacc[2] = __builtin_amdgcn_mfma_f32_16x16x32_bf16(a2, x, sacc[2], 0, 0, 0);
      sacc[3] = __builtin_amdgcn_mfma_f32_16x16x32_bf16(a3, x, sacc[3], 0, 0, 0);
    }
  } else {
    short8 an[4];
    short8 xn = ld_x(xs, 0, l);
#pragma unroll
    for (int m = 0; m < 4; ++m) an[m] = wp[m * 32];
    wp += 1024;

    for (int ii = 0; ii < IPC; ++ii) {
      short8 ac[4];
#pragma unroll
      for (int m = 0; m < 4; ++m) ac[m] = an[m];
      short8 xc = xn;
      if (ii + 1 < IPC) {                    // prefetch rides across barrier
        xn = ld_x(xs, ii + 1, l);
#pragma unroll
        for (int m = 0; m < 4; ++m) an[m] = wp[m * 32];
        wp += 1024;
      }

      const f32x4 z = {0.f, 0.f, 0.f, 0.f};
      f32x4 d[4];
#pragma unroll
      for (int m = 0; m < 4; ++m)
        d[m] = __builtin_amdgcn_mfma_f32_16x16x32_bf16(ac[m], xc, z, 0, 0, 0);
      // d[m][r] = U[o=w*4+m][h=q*4+r][b=bl]

      float e[4];
#pragma unroll
      for (int m = 0; m < 4; ++m) {
        f32x4 pr = d[m] * v[m];
        float p = (pr[0] + pr[1]) + (pr[2] + pr[3]);
        p += __shfl_xor(p, 16);
        p += __shfl_xor(p, 32);
        e[m] = __expf(p);
      }
      const float esum = (e[0] + e[1]) + (e[2] + e[3]);
      if (q == 0) part[ii & 1][w][bl] = esum;
      __syncthreads();
      float den = 0.f;
#pragma unroll
      for (int ww = 0; ww < 8; ++ww) den += part[ii & 1][ww][bl];
      const float rden = __builtin_amdgcn_rcpf(den);
#pragma unroll
      for (int m = 0; m < 4; ++m) sacc[m] += d[m] * (e[m] * rden);
      // part[parity] reuse two iters later is fenced by the barrier between
    }
  }

  // ---- stream partials to P (plain stores; proven in round 5) ----
  float* pp = P + ((size_t)iblk * 128 + bg * 16 + bl) * 512 + w * 64 + q * 4;
#pragma unroll
  for (int m = 0; m < 4; ++m) {
    f32x4 val = sacc[m];
    if constexpr (PASS == 1) val *= (1.f / 32.f);
    *(f32x4*)(pp + m * 16) = val;
  }
}

// ---- reduce over iblk + squash. MODE 0: V1p + Vt. 1: Vt = V1p+sq. 2: Out. --
template <int MODE>
__global__ __launch_bounds__(256)
void reduce_squash(const float* __restrict__ P, float* __restrict__ Vt,
                   float* __restrict__ V1p, float* __restrict__ Out) {
  const int j = blockIdx.x * 256 + threadIdx.x;    // 65536
  float s = 0.f;
  const float* p = P + j;
#pragma unroll 8
  for (int k = 0; k < NBLK_I; ++k) s += p[(size_t)k * SV_ELEMS];
  float ns = s * s;
  ns += __shfl_xor(ns, 1);
  ns += __shfl_xor(ns, 2);
  ns += __shfl_xor(ns, 4);
  ns += __shfl_xor(ns, 8);
  const float sc = ns / ((1.f + ns) * sqrtf(ns));
  float vv = s * sc;
  if constexpr (MODE == 2) {
    Out[j] = vv;
  } else {
    if constexpr (MODE == 0) V1p[j] = vv;
    if constexpr (MODE == 1) vv += V1p[j];     // Vsum = V1+V2 (logit linearity)
    const int b = j >> 9, oh = j & 511, o = oh >> 4, h = oh & 15;
    const int bg = b >> 4, bl = b & 15, w = o >> 2, m = o & 3, qq = h >> 2;
    Vt[(((size_t)(bg * 8 + w) * 64 + qq * 16 + bl) * 16) + m * 4 + (h & 3)] = vv;
  }
}

extern "C" void kernel_launch(void* const* d_in, const int* in_sizes, int n_in,
                              void* d_out, int out_size, void* d_ws, size_t ws_size,
                              hipStream_t stream) {
  const float* X  = (const float*)d_in[0];
  const float* Wg = (const float*)d_in[1];
  // d_in[2] = routing_iterations (3, hard-coded)

  float* P   = (float*)d_ws;                         // 128*65536 f = 33.6 MB
  float* Vt  = P + (size_t)NBLK_I * SV_ELEMS;        // 65536 f (frag order)
  float* V1p = Vt + SV_ELEMS;                        // 65536 f (plain)
  unsigned short* Wb = (unsigned short*)(V1p + SV_ELEMS);   // 18.9 MB
  float* out = (float*)d_out;                        // total ws ~53 MB

  conv_w<<<IN_CAPS, 256, 0, stream>>>(Wg, Wb);

  caps_pass<1><<<1024, 512, 0, stream>>>(Wb, X, nullptr, P);
  reduce_squash<0><<<256, 256, 0, stream>>>(P, Vt, V1p, nullptr);

  caps_pass<2><<<1024, 512, 0, stream>>>(Wb, X, Vt, P);
  reduce_squash<1><<<256, 256, 0, stream>>>(P, Vt, V1p, nullptr);

  caps_pass<2><<<1024, 512, 0, stream>>>(Wb, X, Vt, P);
  reduce_squash<2><<<256, 256, 0, stream>>>(P, nullptr, nullptr, out);
}

// Round 10
// 385.651 us; speedup vs baseline: 1.5763x; 1.5763x over previous
//
#include <hip/hip_runtime.h>
#include <hip/hip_bf16.h>

// CapsuleLayerWithRouting: batch=128, in_caps=1152, in_hid=16, out_caps=32,
// out_hid=16, 3 routing iterations (fixed). fp32 in/out.
//
// Round-10: round 9 minus the poison. Round 9's __launch_bounds__(512,8)
// forced VGPR=32 -> ~800 MB/pass of scratch spill traffic (FETCH 292 MB,
// WRITE 506 MB, 241 us/pass). Restore (512,4): compiler lands ~48-60 VGPR
// for this loop shape (measured r3/r8), which is <=64, so the 1024-block
// grid still reaches 4 blocks/CU (8 waves/SIMD) at runtime — the occupancy
// win round 9 was after — with zero spills. Everything else identical to
// round 9: IPC=9, grid = 128 iblk x 8 bg, bx=bg*128+iblk keeps all 8
// sharers of a Wb slice on XCD iblk%8 (per-XCD Wb 2.3 MB < 4 MB L2),
// plain P-stores + 3 tiny reduce/squash kernels, no atomics, no memsets.
// Fragment layouts (HW-verified m89/m91):
//   A[m=lane&15][k=(lane>>4)*8+j]  B[k=(lane>>4)*8+j][n=lane&15]
//   D[row=(lane>>4)*4+reg][col=lane&15];  K padded 16->32 via zeros in xs.

#define IN_CAPS 1152
#define IPC 9
#define NBLK_I 128                           // 1152/9
#define SV_ELEMS 65536                       // 128*32*16

typedef __attribute__((ext_vector_type(8))) short short8;
typedef __attribute__((ext_vector_type(4))) float f32x4;

__device__ inline unsigned f2bf(float x) {   // RNE fp32 -> bf16
  unsigned u = __builtin_bit_cast(unsigned, x);
  return (u + 0x7FFFu + ((u >> 16) & 1u)) >> 16;
}

// ---- W [1152][16][512] fp32 -> Wb [i][o][lane(32)][8] bf16 (A-frag);
// LDS-staged so reads and writes are both coalesced. ----
__global__ __launch_bounds__(256)
void conv_w(const float* __restrict__ W, unsigned short* __restrict__ Wb) {
  __shared__ float st[16 * 516];
  const int t = threadIdx.x;
  const size_t ibase = (size_t)blockIdx.x * 8192;
  const float4* src = (const float4*)(W + ibase);
#pragma unroll
  for (int r = 0; r < 8; ++r) {
    const int f = r * 256 + t;                // 0..2047 float4s
    const int k = f >> 7, c4 = f & 127;
    *(float4*)&st[k * 516 + c4 * 4] = src[f];
  }
  __syncthreads();
  unsigned short* dst = Wb + ibase;
#pragma unroll
  for (int r = 0; r < 4; ++r) {
    const int u = r * 256 + t;                // 0..1023 = o*32 + l
    const int o = u >> 5, l = u & 31;
    const int col = o * 16 + (l & 15), k0 = (l >> 4) * 8;
    unsigned b[8];
#pragma unroll
    for (int j = 0; j < 8; ++j) b[j] = f2bf(st[(k0 + j) * 516 + col]);
    uint4 outv;
    outv.x = b[0] | (b[1] << 16);
    outv.y = b[2] | (b[3] << 16);
    outv.z = b[4] | (b[5] << 16);
    outv.w = b[6] | (b[7] << 16);
    *(uint4*)(dst + (size_t)u * 8) = outv;    // consecutive u -> coalesced
  }
}

// ---- x B-fragment slice in LDS; zeros in lanes 32-63 (K pad 16->32) ----
__device__ __forceinline__ void build_xs(const float* __restrict__ X, int bg,
                                         int i0, int t, unsigned (*xs)[64][4]) {
#pragma unroll
  for (int rep = 0; rep < (IPC * 256 + 511) / 512; ++rep) {   // 5 (last half)
    const int base = rep * 512 + t;
    if (base < IPC * 256) {
      const int ii = base >> 8;
      const int e = base & 255;
      const int l2 = e >> 2, ju = e & 3;
      unsigned val = 0;
      if (l2 < 32) {
        const float2 f = *(const float2*)(X +
            ((size_t)(bg * 16 + (l2 & 15)) * IN_CAPS + (i0 + ii)) * 16 +
            (l2 >> 4) * 8 + 2 * ju);
        val = f2bf(f.x) | (f2bf(f.y) << 16);
      }
      xs[ii][l2][ju] = val;
    }
  }
}

__device__ __forceinline__ short8 ld_x(const unsigned (*xs)[64][4], int ii, int l) {
  return __builtin_bit_cast(short8, *(const uint4*)(&xs[ii][l][0]));
}

// ---- pass kernel. PASS==1: C=1/32 uniform; PASS==2: dot/softmax/accum ----
template <int PASS>
__global__ __launch_bounds__(512, 4)
void caps_pass(const unsigned short* __restrict__ Wb,
               const float* __restrict__ X,
               const float* __restrict__ Vt,    // frag order (PASS==2)
               float* __restrict__ P) {         // [NBLK_I][128][512]
  __shared__ __align__(16) unsigned xs[IPC][64][4];   // 9.2 KB
  __shared__ float part[2][8][16];

  const int t = threadIdx.x, w = t >> 6, l = t & 63;
  const int q = l >> 4, bl = l & 15;
  const int bx = blockIdx.x, iblk = bx & 127, bg = bx >> 7;  // XCD = iblk%8
  const int i0 = iblk * IPC;

  f32x4 v[4], sacc[4];
#pragma unroll
  for (int m = 0; m < 4; ++m) {
    sacc[m] = (f32x4){0.f, 0.f, 0.f, 0.f};
    if constexpr (PASS == 2)
      v[m] = ((const f32x4*)Vt)[((size_t)(bg * 8 + w) * 64 + l) * 4 + m];
  }

  build_xs(X, bg, i0, t, xs);
  __syncthreads();

  const short8* wp = (const short8*)Wb + ((size_t)i0 * 32 + w * 4) * 32 + (l & 31);

  if constexpr (PASS == 1) {
    for (int ii = 0; ii < IPC; ++ii) {
      short8 x = ld_x(xs, ii, l);
      short8 a0 = wp[0], a1 = wp[32], a2 = wp[64], a3 = wp[96];
      wp += 1024;
      sacc[0] = __builtin_amdgcn_mfma_f32_16x16x32_bf16(a0, x, sacc[0], 0, 0, 0);
      sacc[1] = __builtin_amdgcn_mfma_f32_16x16x32_bf16(a1, x, sacc[1], 0, 0, 0);
      sacc[2] = __builtin_amdgcn_mfma_f32_16x16x32_bf16(a2, x, sacc[2], 0, 0, 0);
      sacc[3] = __builtin_amdgcn_mfma_f32_16x16x32_bf16(a3, x, sacc[3], 0, 0, 0);
    }
  } else {
    short8 an[4];
    short8 xn = ld_x(xs, 0, l);
#pragma unroll
    for (int m = 0; m < 4; ++m) an[m] = wp[m * 32];
    wp += 1024;

    for (int ii = 0; ii < IPC; ++ii) {
      short8 ac[4];
#pragma unroll
      for (int m = 0; m < 4; ++m) ac[m] = an[m];
      short8 xc = xn;
      if (ii + 1 < IPC) {                    // prefetch rides across barrier
        xn = ld_x(xs, ii + 1, l);
#pragma unroll
        for (int m = 0; m < 4; ++m) an[m] = wp[m * 32];
        wp += 1024;
      }

      const f32x4 z = {0.f, 0.f, 0.f, 0.f};
      f32x4 d[4];
#pragma unroll
      for (int m = 0; m < 4; ++m)
        d[m] = __builtin_amdgcn_mfma_f32_16x16x32_bf16(ac[m], xc, z, 0, 0, 0);
      // d[m][r] = U[o=w*4+m][h=q*4+r][b=bl]

      float e[4];
#pragma unroll
      for (int m = 0; m < 4; ++m) {
        f32x4 pr = d[m] * v[m];
        float p = (pr[0] + pr[1]) + (pr[2] + pr[3]);
        p += __shfl_xor(p, 16);
        p += __shfl_xor(p, 32);
        e[m] = __expf(p);
      }
      const float esum = (e[0] + e[1]) + (e[2] + e[3]);
      if (q == 0) part[ii & 1][w][bl] = esum;
      __syncthreads();
      float den = 0.f;
#pragma unroll
      for (int ww = 0; ww < 8; ++ww) den += part[ii & 1][ww][bl];
      const float rden = __builtin_amdgcn_rcpf(den);
#pragma unroll
      for (int m = 0; m < 4; ++m) sacc[m] += d[m] * (e[m] * rden);
      // part[parity] reuse two iters later is fenced by the barrier between
    }
  }

  // ---- stream partials to P (plain stores; proven in round 5) ----
  float* pp = P + ((size_t)iblk * 128 + bg * 16 + bl) * 512 + w * 64 + q * 4;
#pragma unroll
  for (int m = 0; m < 4; ++m) {
    f32x4 val = sacc[m];
    if constexpr (PASS == 1) val *= (1.f / 32.f);
    *(f32x4*)(pp + m * 16) = val;
  }
}

// ---- reduce over iblk + squash. MODE 0: V1p + Vt. 1: Vt = V1p+sq. 2: Out. --
template <int MODE>
__global__ __launch_bounds__(256)
void reduce_squash(const float* __restrict__ P, float* __restrict__ Vt,
                   float* __restrict__ V1p, float* __restrict__ Out) {
  const int j = blockIdx.x * 256 + threadIdx.x;    // 65536
  float s = 0.f;
  const float* p = P + j;
#pragma unroll 8
  for (int k = 0; k < NBLK_I; ++k) s += p[(size_t)k * SV_ELEMS];
  float ns = s * s;
  ns += __shfl_xor(ns, 1);
  ns += __shfl_xor(ns, 2);
  ns += __shfl_xor(ns, 4);
  ns += __shfl_xor(ns, 8);
  const float sc = ns / ((1.f + ns) * sqrtf(ns));
  float vv = s * sc;
  if constexpr (MODE == 2) {
    Out[j] = vv;
  } else {
    if constexpr (MODE == 0) V1p[j] = vv;
    if constexpr (MODE == 1) vv += V1p[j];     // Vsum = V1+V2 (logit linearity)
    const int b = j >> 9, oh = j & 511, o = oh >> 4, h = oh & 15;
    const int bg = b >> 4, bl = b & 15, w = o >> 2, m = o & 3, qq = h >> 2;
    Vt[(((size_t)(bg * 8 + w) * 64 + qq * 16 + bl) * 16) + m * 4 + (h & 3)] = vv;
  }
}

extern "C" void kernel_launch(void* const* d_in, const int* in_sizes, int n_in,
                              void* d_out, int out_size, void* d_ws, size_t ws_size,
                              hipStream_t stream) {
  const float* X  = (const float*)d_in[0];
  const float* Wg = (const float*)d_in[1];
  // d_in[2] = routing_iterations (3, hard-coded)

  float* P   = (float*)d_ws;                         // 128*65536 f = 33.6 MB
  float* Vt  = P + (size_t)NBLK_I * SV_ELEMS;        // 65536 f (frag order)
  float* V1p = Vt + SV_ELEMS;                        // 65536 f (plain)
  unsigned short* Wb = (unsigned short*)(V1p + SV_ELEMS);   // 18.9 MB
  float* out = (float*)d_out;                        // total ws ~53 MB

  conv_w<<<IN_CAPS, 256, 0, stream>>>(Wg, Wb);

  caps_pass<1><<<1024, 512, 0, stream>>>(Wb, X, nullptr, P);
  reduce_squash<0><<<256, 256, 0, stream>>>(P, Vt, V1p, nullptr);

  caps_pass<2><<<1024, 512, 0, stream>>>(Wb, X, Vt, P);
  reduce_squash<1><<<256, 256, 0, stream>>>(P, Vt, V1p, nullptr);

  caps_pass<2><<<1024, 512, 0, stream>>>(Wb, X, Vt, P);
  reduce_squash<2><<<256, 256, 0, stream>>>(P, nullptr, nullptr, out);
}